// Round 6
// baseline (15827.559 us; speedup 1.0000x reference)
//
#include <hip/hip_runtime.h>
#include <math.h>

#define NDIM 64
#define PITCH 68          // chunk-row pitch in words: float4-aligned, conflict-free
#define KC 16             // columns staged per reconstruction chunk
#define MAXSWEEPS 20
#define WPB 4             // waves (= matrices) per 256-thread workgroup

// One wave (64 lanes) per 64x64 SPD matrix. Lane j owns column j in registers.
// One-sided (Hestenes) Jacobi, XOR pair ordering, alternating direction per sweep.
//
// Round-6: rounds 1/5 proved the kernel is NOT occupancy-limited (1-wave and
// 4-wave blocks identical at VGPR 84: 5.7ms, 31% occ, 32% VALU) — the binding
// resource is the per-CU shared DS pipe, saturated by ~128 ds_bpermute per
// rotation (64 for y2, re-fetched in the update because y2 can't stay live at
// 84 regs). Fix: the partner is lane^m, a pure XOR pattern — decompose every
// m into VALU cross-lane stages (DPP quad_perm xor1/2/3, row_half_mirror xor7,
// row_ror:8 xor8, permlane16/32_swap xor16/32), selected by wave-uniform
// runtime branches. permlane*_swap orientation is SELF-TESTED at kernel entry
// on the lane-id pattern (data-oblivious op => test validity for all data);
// fallback to ds_swizzle(xor16) / full ds_bpermute if unavailable/wrong.
// Branchy stages force y2 fully live -> launch_bounds(.,1) removes the reg cap
// (VGPR ~150, one occupancy bucket down — a good trade for killing the DS pipe
// serialization AND the double-fetch).
typedef float v2f __attribute__((ext_vector_type(2)));
typedef unsigned int uint2v __attribute__((ext_vector_type(2)));

__device__ __forceinline__ v2f pk_fma(v2f a, v2f b, v2f c)
{
    v2f d;
    asm("v_pk_fma_f32 %0, %1, %2, %3" : "=v"(d) : "v"(a), "v"(b), "v"(c));
    return d;
}

__device__ __forceinline__ v2f pk_mul(v2f a, v2f b)
{
    v2f d;
    asm("v_pk_mul_f32 %0, %1, %2" : "=v"(d) : "v"(a), "v"(b));
    return d;
}

// DPP xor-exchange ctrl values (full permutations within 16-lane rows)
#define DPP_XOR1 0xB1     // quad_perm [1,0,3,2]
#define DPP_XOR2 0x4E     // quad_perm [2,3,0,1]
#define DPP_XOR3 0x1B     // quad_perm [3,2,1,0]
#define DPP_XOR7 0x141    // row_half_mirror
#define DPP_XOR8 0x128    // row_ror:8  ((l+8)&15 == l^8)

template<int CTRL>
__device__ __forceinline__ float dppf(float v)
{
    return __int_as_float(__builtin_amdgcn_mov_dpp(__float_as_int(v), CTRL, 0xF, 0xF, true));
}

__device__ __forceinline__ float swz16f(float v)   // xor16 via ds_swizzle (always correct)
{
    return __int_as_float(__builtin_amdgcn_ds_swizzle(__float_as_int(v), 0x401F));
}

__device__ __forceinline__ float bpermf(int pidx, float v)
{
    return __int_as_float(__builtin_amdgcn_ds_bpermute(pidx, __float_as_int(v)));
}

__global__ __launch_bounds__(WPB * 64, 1)
void logeig_jacobi_kernel(const float* __restrict__ in, float* __restrict__ out)
{
    const int wid  = threadIdx.x >> 6;    // wave id within block = matrix slot
    const int lane = threadIdx.x & 63;
    const int b    = blockIdx.x * WPB + wid;
    const float* A = in  + (size_t)b * (NDIM * NDIM);
    float*       O = out + (size_t)b * (NDIM * NDIM);

    __shared__ float ldsM[WPB][KC * PITCH];   // per-wave staged columns
    __shared__ float ldsW[WPB][NDIM];         // per-wave column weights

    // ---- self-test permlane swap orientation (once; uniform results) ----
    bool have32 = false, have16 = false;
    bool pickY32 = false, pickY16 = false;   // per-lane: take r.y (else r.x)
#if __has_builtin(__builtin_amdgcn_permlane32_swap)
    {
        uint2v r = __builtin_amdgcn_permlane32_swap((unsigned)lane, (unsigned)lane, false, false);
        const unsigned want = (unsigned)(lane ^ 32);
        const bool okA = (__ballot(((lane < 32) ? r.y : r.x) == want) == ~0ull);
        const bool okC = (__ballot(((lane < 32) ? r.x : r.y) == want) == ~0ull);
        have32  = okA || okC;
        pickY32 = (okA == (lane < 32));
    }
#endif
#if __has_builtin(__builtin_amdgcn_permlane16_swap)
    {
        uint2v r = __builtin_amdgcn_permlane16_swap((unsigned)lane, (unsigned)lane, false, false);
        const unsigned want = (unsigned)(lane ^ 16);
        const bool okA = (__ballot((((lane & 16) == 0) ? r.y : r.x) == want) == ~0ull);
        const bool okC = (__ballot((((lane & 16) == 0) ? r.x : r.y) == want) == ~0ull);
        have16  = okA || okC;
        pickY16 = (okA == ((lane & 16) == 0));
    }
#endif

    auto p32w = [&](float v) -> float {
#if __has_builtin(__builtin_amdgcn_permlane32_swap)
        uint2v r = __builtin_amdgcn_permlane32_swap(__float_as_uint(v), __float_as_uint(v), false, false);
        return __uint_as_float(pickY32 ? r.y : r.x);
#else
        return v;
#endif
    };
    auto p16w = [&](float v) -> float {
#if __has_builtin(__builtin_amdgcn_permlane16_swap)
        uint2v r = __builtin_amdgcn_permlane16_swap(__float_as_uint(v), __float_as_uint(v), false, false);
        return __uint_as_float(pickY16 ? r.y : r.x);
#else
        return v;
#endif
    };

    // stage in: column 'lane' of A, packed as 32 float2 pairs; coalesced across lanes
    v2f x2[NDIM / 2];
#pragma unroll
    for (int i = 0; i < NDIM / 2; ++i) {
        x2[i].x = A[(2 * i + 0) * NDIM + lane];
        x2[i].y = A[(2 * i + 1) * NDIM + lane];
    }

    float alpha = 0.0f;   // refreshed at each sweep start before first use

// stage application: exchanges alpha-carrier 'aex' and the y2 array together.
// First active stage reads from x2, later stages transform y2 in place.
#define EX_STAGE(COND, OPX)                                                      \
    if (COND) {                                                                  \
        aex = OPX(aex);                                                          \
        if (first) {                                                             \
            _Pragma("unroll")                                                    \
            for (int i = 0; i < NDIM / 2; ++i) {                                 \
                y2[i].x = OPX(x2[i].x); y2[i].y = OPX(x2[i].y);                  \
            }                                                                    \
            first = false;                                                       \
        } else {                                                                 \
            _Pragma("unroll")                                                    \
            for (int i = 0; i < NDIM / 2; ++i) {                                 \
                y2[i].x = OPX(y2[i].x); y2[i].y = OPX(y2[i].y);                  \
            }                                                                    \
        }                                                                        \
    }

#pragma unroll 1
    for (int sweep = 0; sweep < MAXSWEEPS; ++sweep) {
        // refresh self-dot (kills incremental-update drift); packed, 2 chains
        v2f r0 = {0.f, 0.f}, r1 = {0.f, 0.f};
#pragma unroll
        for (int i = 0; i < NDIM / 2; i += 2) {
            r0 = pk_fma(x2[i],     x2[i],     r0);
            r1 = pk_fma(x2[i + 1], x2[i + 1], r1);
        }
        alpha = (r0.x + r0.y) + (r1.x + r1.y);

        bool any_big = false;   // per-lane; one ballot per sweep
#pragma unroll 1
        for (int mi = 1; mi < NDIM; ++mi) {
            const int m = (sweep & 1) ? (NDIM - mi) : mi;  // alternate direction

            // ---- partner exchange: y2[lane] = x2[lane^m], aex = alpha[lane^m] ----
            v2f  y2[NDIM / 2];
            float aex = alpha;
            bool  first = true;
            const bool useBperm = ((m & 32) != 0) && !have32;   // uniform
            if (useBperm) {
                const int pidx = (lane ^ m) << 2;
#pragma unroll
                for (int i = 0; i < NDIM / 2; ++i) {
                    y2[i].x = bpermf(pidx, x2[i].x);
                    y2[i].y = bpermf(pidx, x2[i].y);
                }
                aex = bpermf(pidx, alpha);
                first = false;
            } else {
                const int  lo = m & 15;
                const bool u7 = (lo & 4) != 0;
                const int  r2 = (u7 ? (lo ^ 7) : lo) & 3;
                EX_STAGE((m & 32) != 0, p32w)
                EX_STAGE(((m & 16) != 0) && have16, p16w)
                EX_STAGE(((m & 16) != 0) && !have16, swz16f)
                EX_STAGE((lo & 8) != 0, dppf<DPP_XOR8>)
                EX_STAGE(u7,            dppf<DPP_XOR7>)
                EX_STAGE(r2 == 3,       dppf<DPP_XOR3>)
                EX_STAGE(r2 == 2,       dppf<DPP_XOR2>)
                EX_STAGE(r2 == 1,       dppf<DPP_XOR1>)
            }

            // cross dot, packed, 2 chains; product order identical on both lanes
            // of a pair (mult commutes, same grouping) -> bitwise-same gamma
            v2f g0 = {0.f, 0.f}, g1 = {0.f, 0.f};
#pragma unroll
            for (int i = 0; i < NDIM / 2; i += 2) {
                g0 = pk_fma(x2[i],     y2[i],     g0);
                g1 = pk_fma(x2[i + 1], y2[i + 1], g1);
            }
            const float gamma = (g0.x + g0.y) + (g1.x + g1.y);

            const bool  is_p = lane < (lane ^ m);
            const float aa = is_p ? alpha : aex;  // alpha (p's self-dot)
            const float bb = is_p ? aex : alpha;  // beta  (q's self-dot)

            // convergence detector ONLY (rel 3.2e-5 > fp32 dot noise ~5e-7);
            // does not gate the rotation -> no stagnation
            any_big = any_big || ((gamma * gamma) > (1e-9f * aa * bb));

            // Golub-Van-Loan symmetric Schur, division-free:
            //   w = 2*gamma, d = bb-aa
            //   t = sign(d)*w / (|d| + sqrt(w^2 + d^2))   (== sign(z)/(|z|+sqrt(1+z^2)))
            // 1e-35 floor inside the sqrt keeps the w-denormal/d==0 corner finite;
            // w,d identical on both lanes of a pair -> bitwise-same t,c,s.
            const bool  rot = (gamma != 0.0f);
            const float w   = 2.0f * gamma;
            const float d   = bb - aa;
            const float den = fabsf(d) + __builtin_amdgcn_sqrtf(fmaf(w, w, fmaf(d, d, 1e-35f)));
            const float t   = ((d >= 0.0f) ? w : -w) * __builtin_amdgcn_rcpf(den);
            const float cc  = __builtin_amdgcn_rsqf(fmaf(t, t, 1.0f));
            const float ss  = t * cc;

            const float sgn = is_p ? -1.0f : 1.0f;  // p: x' = c x - s y ; q: x' = c x + s y
            const float c_r = rot ? cc : 1.0f;
            const float s_r = rot ? sgn * ss : 0.0f;
            const float tg  = rot ? sgn * t * gamma : 0.0f;

            v2f c2; c2.x = c_r; c2.y = c_r;
            v2f s2; s2.x = s_r; s2.y = s_r;
#pragma unroll
            for (int i = 0; i < NDIM / 2; ++i)
                x2[i] = pk_fma(c2, x2[i], pk_mul(s2, y2[i]));
            alpha += tg;                            // alpha' = alpha -/+ t*gamma
        }
        if (__ballot(any_big) == 0ull) break;   // all pairs below rel 3.2e-5 -> converged
    }

    // eigenvalue & weight: lambda = ||m||, w = log(lambda + 1e-9) / lambda^2
    v2f f0 = {0.f, 0.f}, f1 = {0.f, 0.f};
#pragma unroll
    for (int i = 0; i < NDIM / 2; i += 2) {
        f0 = pk_fma(x2[i],     x2[i],     f0);
        f1 = pk_fma(x2[i + 1], x2[i + 1], f1);
    }
    const float af  = (f0.x + f0.y) + (f1.x + f1.y);
    const float lam = __builtin_amdgcn_sqrtf(af);
    ldsW[wid][lane] = logf(lam + 1e-9f) / af;   // same-wave DS order makes this visible below

    // O[:,lane] = sum_k (w_k * m_{lane,k}) * m_{:,k}, staged KC columns at a time.
    // All LDS traffic is private to this wave; DS ops execute in program order
    // within a wave, so no barriers are needed between write and read phases.
    v2f acc2[NDIM / 2];
#pragma unroll
    for (int i = 0; i < NDIM / 2; ++i) { acc2[i].x = 0.f; acc2[i].y = 0.f; }

#pragma unroll 1
    for (int c = 0; c < NDIM; c += KC) {
        if (lane >= c && lane < c + KC) {
            float4* row = (float4*)&ldsM[wid][(lane - c) * PITCH];
#pragma unroll
            for (int t4 = 0; t4 < NDIM / 4; ++t4)
                row[t4] = make_float4(x2[2 * t4].x, x2[2 * t4].y,
                                      x2[2 * t4 + 1].x, x2[2 * t4 + 1].y);
        }
#pragma unroll 1
        for (int kk = 0; kk < KC; ++kk) {
            const float wk  = ldsW[wid][c + kk];             // broadcast
            const float mlk = ldsM[wid][kk * PITCH + lane];  // consecutive -> conflict-free
            const float zk  = wk * mlk;
            v2f zk2; zk2.x = zk; zk2.y = zk;
            const float4* rowk = (const float4*)&ldsM[wid][kk * PITCH];
#pragma unroll
            for (int t4 = 0; t4 < NDIM / 4; ++t4) {
                const float4 v = rowk[t4];              // broadcast float4
                v2f lo; lo.x = v.x; lo.y = v.y;
                v2f hi; hi.x = v.z; hi.y = v.w;
                acc2[2 * t4]     = pk_fma(zk2, lo, acc2[2 * t4]);
                acc2[2 * t4 + 1] = pk_fma(zk2, hi, acc2[2 * t4 + 1]);
            }
        }
    }

#pragma unroll
    for (int i = 0; i < NDIM / 2; ++i) {
        O[(2 * i + 0) * NDIM + lane] = acc2[i].x;   // coalesced across lanes
        O[(2 * i + 1) * NDIM + lane] = acc2[i].y;
    }
}

extern "C" void kernel_launch(void* const* d_in, const int* in_sizes, int n_in,
                              void* d_out, int out_size, void* d_ws, size_t ws_size,
                              hipStream_t stream)
{
    const float* in  = (const float*)d_in[0];
    float*       out = (float*)d_out;
    const int nmat = out_size / (NDIM * NDIM);   // 256*32 = 8192
    hipLaunchKernelGGL(logeig_jacobi_kernel, dim3(nmat / WPB), dim3(WPB * 64), 0, stream, in, out);
}

// Round 7
// 5656.847 us; speedup vs baseline: 2.7979x; 2.7979x over previous
//
#include <hip/hip_runtime.h>
#include <math.h>

#define NDIM 64
#define PITCH 68          // chunk-row pitch in words: float4-aligned, conflict-free
#define KC 16             // columns staged per reconstruction chunk
#define MAXSWEEPS 20
#define WPB 4             // waves (= matrices) per 256-thread workgroup

// One wave (64 lanes) per 64x64 SPD matrix. Lane j owns column j in registers.
// One-sided (Hestenes) Jacobi, XOR pair ordering, alternating direction per sweep.
//
// Round-7: the kernel is DS-pipe-bound. Evidence: round-5 runtime (13.85M cyc)
// == 129 DS ops/rot x 4.8cyc x 693 rot x 32 mat/CU (13.7M); round-6's VALU-side
// exchange (DPP/permlane decomposition) exploded to 5x VALU work and 16ms —
// DS theory stands, that implementation was the failure. Here: keep round-5's
// bpermute exchange EXACTLY, but remove the register cap (launch_bounds(256,1)
// -> cap 256 per the validated cap=256/min_waves model) so y2 survives
// dot->schur->update and the 64-op refetch disappears: 129 -> 65 DS ops/rot.
// Occupancy drops to ~5 waves/CU (measured law: waves/CU ~ 840/VGPR) but the
// DS pipe is CU-shared — 5 waves x ~312 DS-cyc per ~600-cyc rotation keep it
// saturated. Predicted DS-bound floor ~6.9M cyc ~ 2.9ms.
// Waves never sync: each uses a private LDS slice; intra-wave DS program
// order replaces all __syncthreads in the reconstruction.
typedef float v2f __attribute__((ext_vector_type(2)));

__device__ __forceinline__ v2f pk_fma(v2f a, v2f b, v2f c)
{
    v2f d;
    asm("v_pk_fma_f32 %0, %1, %2, %3" : "=v"(d) : "v"(a), "v"(b), "v"(c));
    return d;
}

__device__ __forceinline__ v2f pk_mul(v2f a, v2f b)
{
    v2f d;
    asm("v_pk_mul_f32 %0, %1, %2" : "=v"(d) : "v"(a), "v"(b));
    return d;
}

__global__ __launch_bounds__(WPB * 64, 1)
void logeig_jacobi_kernel(const float* __restrict__ in, float* __restrict__ out)
{
    const int wid  = threadIdx.x >> 6;    // wave id within block = matrix slot
    const int lane = threadIdx.x & 63;
    const int b    = blockIdx.x * WPB + wid;
    const float* A = in  + (size_t)b * (NDIM * NDIM);
    float*       O = out + (size_t)b * (NDIM * NDIM);

    __shared__ float ldsM[WPB][KC * PITCH];   // per-wave staged columns
    __shared__ float ldsW[WPB][NDIM];         // per-wave column weights

    // stage in: column 'lane' of A, packed as 32 float2 pairs; coalesced across lanes
    v2f x2[NDIM / 2];
#pragma unroll
    for (int i = 0; i < NDIM / 2; ++i) {
        x2[i].x = A[(2 * i + 0) * NDIM + lane];
        x2[i].y = A[(2 * i + 1) * NDIM + lane];
    }

    float alpha = 0.0f;   // refreshed at each sweep start before first use

#pragma unroll 1
    for (int sweep = 0; sweep < MAXSWEEPS; ++sweep) {
        // refresh self-dot (kills incremental-update drift); packed, 2 chains
        v2f r0 = {0.f, 0.f}, r1 = {0.f, 0.f};
#pragma unroll
        for (int i = 0; i < NDIM / 2; i += 2) {
            r0 = pk_fma(x2[i],     x2[i],     r0);
            r1 = pk_fma(x2[i + 1], x2[i + 1], r1);
        }
        alpha = (r0.x + r0.y) + (r1.x + r1.y);

        bool any_big = false;   // per-lane; one ballot per sweep
#pragma unroll 1
        for (int mi = 1; mi < NDIM; ++mi) {
            const int m    = (sweep & 1) ? (NDIM - mi) : mi;  // alternate direction
            const int pidx = (lane ^ m) << 2;

            // pull partner column ONCE (64 b32 bpermutes); y2 stays live through
            // the update — the whole point of the uncapped register budget
            v2f y2[NDIM / 2];
#pragma unroll
            for (int i = 0; i < NDIM / 2; ++i) {
                y2[i].x = __int_as_float(__builtin_amdgcn_ds_bpermute(pidx, __float_as_int(x2[i].x)));
                y2[i].y = __int_as_float(__builtin_amdgcn_ds_bpermute(pidx, __float_as_int(x2[i].y)));
            }

            // cross dot, packed, 2 chains; product order identical on both lanes
            // of a pair (mult commutes, same grouping) -> bitwise-same gamma
            v2f g0 = {0.f, 0.f}, g1 = {0.f, 0.f};
#pragma unroll
            for (int i = 0; i < NDIM / 2; i += 2) {
                g0 = pk_fma(x2[i],     y2[i],     g0);
                g1 = pk_fma(x2[i + 1], y2[i + 1], g1);
            }
            const float gamma = (g0.x + g0.y) + (g1.x + g1.y);

            const float other = __int_as_float(__builtin_amdgcn_ds_bpermute(pidx, __float_as_int(alpha)));

            const bool  is_p = lane < (lane ^ m);
            const float aa = is_p ? alpha : other;  // alpha (p's self-dot)
            const float bb = is_p ? other : alpha;  // beta  (q's self-dot)

            // convergence detector ONLY (rel 3.2e-5 > fp32 dot noise ~5e-7);
            // does not gate the rotation -> no stagnation
            any_big = any_big || ((gamma * gamma) > (1e-9f * aa * bb));

            // Golub-Van-Loan symmetric Schur, division-free:
            //   w = 2*gamma, d = bb-aa
            //   t = sign(d)*w / (|d| + sqrt(w^2 + d^2))   (== sign(z)/(|z|+sqrt(1+z^2)))
            // 1e-35 floor inside the sqrt keeps the w-denormal/d==0 corner finite;
            // w,d identical on both lanes of a pair -> bitwise-same t,c,s.
            const bool  rot = (gamma != 0.0f);
            const float w   = 2.0f * gamma;
            const float d   = bb - aa;
            const float den = fabsf(d) + __builtin_amdgcn_sqrtf(fmaf(w, w, fmaf(d, d, 1e-35f)));
            const float t   = ((d >= 0.0f) ? w : -w) * __builtin_amdgcn_rcpf(den);
            const float cc  = __builtin_amdgcn_rsqf(fmaf(t, t, 1.0f));
            const float ss  = t * cc;

            const float sgn = is_p ? -1.0f : 1.0f;  // p: x' = c x - s y ; q: x' = c x + s y
            const float c_r = rot ? cc : 1.0f;
            const float s_r = rot ? sgn * ss : 0.0f;
            const float tg  = rot ? sgn * t * gamma : 0.0f;

            v2f c2; c2.x = c_r; c2.y = c_r;
            v2f s2; s2.x = s_r; s2.y = s_r;
#pragma unroll
            for (int i = 0; i < NDIM / 2; ++i)
                x2[i] = pk_fma(c2, x2[i], pk_mul(s2, y2[i]));
            alpha += tg;                            // alpha' = alpha -/+ t*gamma
        }
        if (__ballot(any_big) == 0ull) break;   // all pairs below rel 3.2e-5 -> converged
    }

    // eigenvalue & weight: lambda = ||m||, w = log(lambda + 1e-9) / lambda^2
    v2f f0 = {0.f, 0.f}, f1 = {0.f, 0.f};
#pragma unroll
    for (int i = 0; i < NDIM / 2; i += 2) {
        f0 = pk_fma(x2[i],     x2[i],     f0);
        f1 = pk_fma(x2[i + 1], x2[i + 1], f1);
    }
    const float af  = (f0.x + f0.y) + (f1.x + f1.y);
    const float lam = __builtin_amdgcn_sqrtf(af);
    ldsW[wid][lane] = logf(lam + 1e-9f) / af;   // same-wave DS order makes this visible below

    // O[:,lane] = sum_k (w_k * m_{lane,k}) * m_{:,k}, staged KC columns at a time.
    // All LDS traffic is private to this wave; DS ops execute in program order
    // within a wave, so no barriers are needed between write and read phases.
    v2f acc2[NDIM / 2];
#pragma unroll
    for (int i = 0; i < NDIM / 2; ++i) { acc2[i].x = 0.f; acc2[i].y = 0.f; }

#pragma unroll 1
    for (int c = 0; c < NDIM; c += KC) {
        if (lane >= c && lane < c + KC) {
            float4* row = (float4*)&ldsM[wid][(lane - c) * PITCH];
#pragma unroll
            for (int t4 = 0; t4 < NDIM / 4; ++t4)
                row[t4] = make_float4(x2[2 * t4].x, x2[2 * t4].y,
                                      x2[2 * t4 + 1].x, x2[2 * t4 + 1].y);
        }
#pragma unroll 1
        for (int kk = 0; kk < KC; ++kk) {
            const float wk  = ldsW[wid][c + kk];             // broadcast
            const float mlk = ldsM[wid][kk * PITCH + lane];  // consecutive -> conflict-free
            const float zk  = wk * mlk;
            v2f zk2; zk2.x = zk; zk2.y = zk;
            const float4* rowk = (const float4*)&ldsM[wid][kk * PITCH];
#pragma unroll
            for (int t4 = 0; t4 < NDIM / 4; ++t4) {
                const float4 v = rowk[t4];              // broadcast float4
                v2f lo; lo.x = v.x; lo.y = v.y;
                v2f hi; hi.x = v.z; hi.y = v.w;
                acc2[2 * t4]     = pk_fma(zk2, lo, acc2[2 * t4]);
                acc2[2 * t4 + 1] = pk_fma(zk2, hi, acc2[2 * t4 + 1]);
            }
        }
    }

#pragma unroll
    for (int i = 0; i < NDIM / 2; ++i) {
        O[(2 * i + 0) * NDIM + lane] = acc2[i].x;   // coalesced across lanes
        O[(2 * i + 1) * NDIM + lane] = acc2[i].y;
    }
}

extern "C" void kernel_launch(void* const* d_in, const int* in_sizes, int n_in,
                              void* d_out, int out_size, void* d_ws, size_t ws_size,
                              hipStream_t stream)
{
    const float* in  = (const float*)d_in[0];
    float*       out = (float*)d_out;
    const int nmat = out_size / (NDIM * NDIM);   // 256*32 = 8192
    hipLaunchKernelGGL(logeig_jacobi_kernel, dim3(nmat / WPB), dim3(WPB * 64), 0, stream, in, out);
}